// Round 10
// baseline (305.507 us; speedup 1.0000x reference)
//
#include <hip/hip_runtime.h>

typedef short short8 __attribute__((ext_vector_type(8)));
typedef float f32x4 __attribute__((ext_vector_type(4)));
typedef float f32x16 __attribute__((ext_vector_type(16)));

#define MFMA16(a,b,c) __builtin_amdgcn_mfma_f32_16x16x32_bf16((a),(b),(c),0,0,0)
#define MFMA32(a,b,c) __builtin_amdgcn_mfma_f32_32x32x16_bf16((a),(b),(c),0,0,0)

__device__ __forceinline__ unsigned short f2bf(float f) {
    unsigned u = __float_as_uint(f);
    u += 0x7fff + ((u >> 16) & 1);      // rne
    return (unsigned short)(u >> 16);
}
__device__ __forceinline__ float bf2f(unsigned short h) {
    return __uint_as_float(((unsigned)h) << 16);
}
__device__ __forceinline__ unsigned cvt_pk_bf16(float a, float b) {
    unsigned r;
    asm("v_cvt_pk_bf16_f32 %0, %1, %2" : "=v"(r) : "v"(a), "v"(b));
    return r;   // lo16 = bf16(a), hi16 = bf16(b)
}
__device__ __forceinline__ short8 mk8(unsigned a, unsigned b, unsigned c, unsigned d) {
    union { unsigned u[4]; short8 s; } x;
    x.u[0] = a; x.u[1] = b; x.u[2] = c; x.u[3] = d;
    return x.s;
}

// ---------------------------------------------------------------------------
// fp32 -> (hi, lo) bf16 plane split for the 4 weight matrices.
// ---------------------------------------------------------------------------
struct ConvJob  { const float* src; short* hi; short* lo; int n8; };
struct ConvArgs { ConvJob j[4]; };

__global__ __launch_bounds__(256) void conv_split(ConvArgs a) {
    ConvJob jb = a.j[blockIdx.z];
    const int n8 = jb.n8;
    for (int i = blockIdx.x * blockDim.x + threadIdx.x; i < n8;
         i += gridDim.x * blockDim.x) {
        const float4* s = (const float4*)jb.src + (size_t)i * 2;
        float4 x0 = s[0], x1 = s[1];
        float xs[8] = {x0.x, x0.y, x0.z, x0.w, x1.x, x1.y, x1.z, x1.w};
        short8 h, l;
#pragma unroll
        for (int jj = 0; jj < 8; ++jj) {
            unsigned short hh = f2bf(xs[jj]);
            h[jj] = (short)hh;
            l[jj] = (short)f2bf(xs[jj] - bf2f(hh));
        }
        *(short8*)(jb.hi + (size_t)i * 8) = h;
        *(short8*)(jb.lo + (size_t)i * 8) = l;
    }
}

// ---------------------------------------------------------------------------
// bf16x3-split MFMA GEMM (unchanged from r3/r4 passing version).
// ---------------------------------------------------------------------------
#define PBK 32
#define PLD 40

template<bool BF16, bool SPLITOUT>
__global__ __launch_bounds__(256) void mfma_gemm(
    const void* Xa0, const void* Xb0, const short* Wh0, const short* Wl0, void* Ca0, void* Cb0,
    const void* Xa1, const void* Xb1, const short* Wh1, const short* Wl1, void* Ca1, void* Cb1,
    const void* Xa2, const void* Xb2, const short* Wh2, const short* Wl2, void* Ca2, void* Cb2,
    const float* __restrict__ bias)
{
    const void* Xa; const void* Xb; const short* Whp; const short* Wlp; void* Cp; void* Cq;
    if (blockIdx.z == 0)      { Xa = Xa0; Xb = Xb0; Whp = Wh0; Wlp = Wl0; Cp = Ca0; Cq = Cb0; }
    else if (blockIdx.z == 1) { Xa = Xa1; Xb = Xb1; Whp = Wh1; Wlp = Wl1; Cp = Ca1; Cq = Cb1; }
    else                      { Xa = Xa2; Xb = Xb2; Whp = Wh2; Wlp = Wl2; Cp = Ca2; Cq = Cb2; }

    const float* Xf = (const float*)Xa;
    const short* Xh = (const short*)Xa;
    const short* Xl = (const short*)Xb;

    __shared__ __align__(16) short Ah[128 * PLD];
    __shared__ __align__(16) short Al[128 * PLD];
    __shared__ __align__(16) short Bh[128 * PLD];
    __shared__ __align__(16) short Bl[128 * PLD];

    const int tid = threadIdx.x;
    const int rowBase = blockIdx.x * 128;
    const int colBase = blockIdx.y * 128;
    const int rs = tid >> 1;
    const int kh = tid & 1;
    const int lane = tid & 63;
    const int wv = tid >> 6;
    const int wm = (wv >> 1) * 64;
    const int wn = (wv & 1) * 64;
    const int g = lane >> 4, r = lane & 15;

    f32x4 acc[4][4];
#pragma unroll
    for (int i = 0; i < 4; ++i)
#pragma unroll
        for (int j = 0; j < 4; ++j) acc[i][j] = (f32x4)(0.f);

    short8 sAh0, sAh1, sAl0, sAl1, sBh0, sBh1, sBl0, sBl1;
    float4 sF0, sF1, sF2, sF3;

    auto loadRegs = [&](int kt) {
        const size_t aoff = (size_t)(rowBase + rs) * 512 + kt * PBK + kh * 16;
        const size_t boff = (size_t)(colBase + rs) * 512 + kt * PBK + kh * 16;
        if constexpr (BF16) {
            sAh0 = *(const short8*)(Xh + aoff); sAh1 = *(const short8*)(Xh + aoff + 8);
            sAl0 = *(const short8*)(Xl + aoff); sAl1 = *(const short8*)(Xl + aoff + 8);
        } else {
            sF0 = *(const float4*)(Xf + aoff);      sF1 = *(const float4*)(Xf + aoff + 4);
            sF2 = *(const float4*)(Xf + aoff + 8);  sF3 = *(const float4*)(Xf + aoff + 12);
        }
        sBh0 = *(const short8*)(Whp + boff); sBh1 = *(const short8*)(Whp + boff + 8);
        sBl0 = *(const short8*)(Wlp + boff); sBl1 = *(const short8*)(Wlp + boff + 8);
    };

    auto stageLDS = [&]() {
        const int lb = rs * PLD + kh * 16;
        if constexpr (BF16) {
            *(short8*)&Ah[lb] = sAh0; *(short8*)&Ah[lb + 8] = sAh1;
            *(short8*)&Al[lb] = sAl0; *(short8*)&Al[lb + 8] = sAl1;
        } else {
            float xs[16] = {sF0.x, sF0.y, sF0.z, sF0.w, sF1.x, sF1.y, sF1.z, sF1.w,
                            sF2.x, sF2.y, sF2.z, sF2.w, sF3.x, sF3.y, sF3.z, sF3.w};
            short8 h0, h1, l0, l1;
#pragma unroll
            for (int jj = 0; jj < 8; ++jj) {
                unsigned short ha = f2bf(xs[jj]);
                h0[jj] = (short)ha; l0[jj] = (short)f2bf(xs[jj] - bf2f(ha));
                unsigned short hb = f2bf(xs[8 + jj]);
                h1[jj] = (short)hb; l1[jj] = (short)f2bf(xs[8 + jj] - bf2f(hb));
            }
            *(short8*)&Ah[lb] = h0; *(short8*)&Ah[lb + 8] = h1;
            *(short8*)&Al[lb] = l0; *(short8*)&Al[lb + 8] = l1;
        }
        *(short8*)&Bh[lb] = sBh0; *(short8*)&Bh[lb + 8] = sBh1;
        *(short8*)&Bl[lb] = sBl0; *(short8*)&Bl[lb + 8] = sBl1;
    };

    loadRegs(0);

    for (int kt = 0; kt < 16; ++kt) {
        __syncthreads();
        stageLDS();
        __syncthreads();
        if (kt < 15) loadRegs(kt + 1);

        short8 fah[4], fal[4], fbh[4], fbl[4];
#pragma unroll
        for (int fm = 0; fm < 4; ++fm) {
            const int off = (wm + fm * 16 + r) * PLD + g * 8;
            fah[fm] = *(const short8*)&Ah[off];
            fal[fm] = *(const short8*)&Al[off];
        }
#pragma unroll
        for (int fn = 0; fn < 4; ++fn) {
            const int off = (wn + fn * 16 + r) * PLD + g * 8;
            fbh[fn] = *(const short8*)&Bh[off];
            fbl[fn] = *(const short8*)&Bl[off];
        }
#pragma unroll
        for (int fm = 0; fm < 4; ++fm)
#pragma unroll
            for (int fn = 0; fn < 4; ++fn) {
                acc[fm][fn] = MFMA16(fah[fm], fbh[fn], acc[fm][fn]);
                acc[fm][fn] = MFMA16(fah[fm], fbl[fn], acc[fm][fn]);
                acc[fm][fn] = MFMA16(fal[fm], fbh[fn], acc[fm][fn]);
            }
    }

    if constexpr (SPLITOUT) {
        short* Ch = (short*)Cp;
        short* Cl2 = (short*)Cq;
#pragma unroll
        for (int fm = 0; fm < 4; ++fm)
#pragma unroll
            for (int fn = 0; fn < 4; ++fn) {
                const int col = colBase + wn + fn * 16 + r;
#pragma unroll
                for (int i = 0; i < 4; ++i) {
                    const int row = rowBase + wm + fm * 16 + g * 4 + i;
                    float v = acc[fm][fn][i];
                    unsigned u = __float_as_uint(v);
                    unsigned hi = u & 0xFFFF0000u;
                    float lf = v - __uint_as_float(hi);
                    Ch[(size_t)row * 512 + col]  = (short)(hi >> 16);
                    Cl2[(size_t)row * 512 + col] = (short)(__float_as_uint(lf) >> 16);
                }
            }
    } else {
        float* C = (float*)Cp;
        float bv[4];
#pragma unroll
        for (int fn = 0; fn < 4; ++fn)
            bv[fn] = bias ? bias[colBase + wn + fn * 16 + r] : 0.f;
#pragma unroll
        for (int fm = 0; fm < 4; ++fm)
#pragma unroll
            for (int fn = 0; fn < 4; ++fn) {
                const int col = colBase + wn + fn * 16 + r;
#pragma unroll
                for (int i = 0; i < 4; ++i) {
                    const int row = rowBase + wm + fm * 16 + g * 4 + i;
                    C[(size_t)row * 512 + col] = acc[fm][fn][i] + bv[fn];
                }
            }
    }
}

// ---------------------------------------------------------------------------
// bf16x3-split MFMA flash attention, v2 (+XCD grid orientation, +setprio):
//  - grid(bh, qt): flat id % 8 = bh % 8 -> one (b,h)'s K/V pinned to one XCD
//  - double-buffered K/V LDS, ONE barrier per tile
//  - exp2-domain online softmax
//  - P in registers: cvt_pk_bf16 + lane^32 shfl exchange -> PV B-fragment
//    (exchange verified by two independent derivations, r5+r7)
//  - s_setprio(1) around MFMA clusters (T5: +4-7% attn, m191)
// Layouts (validated r4 pass): MFMA32 lane=32g+r: A[r][8g+j], B[8g+j][r],
// D[row=(reg&3)+8*(reg>>2)+4g][col=r].
// ---------------------------------------------------------------------------
#define ATP 72

__global__ __launch_bounds__(256) void attn_mfma(
    const short* __restrict__ Qh, const short* __restrict__ Ql,
    const short* __restrict__ Kh, const short* __restrict__ Kl,
    const short* __restrict__ Vh, const short* __restrict__ Vl,
    const int* __restrict__ mask,
    short* __restrict__ Oh, short* __restrict__ Ol)
{
    const int S = 2048;
    const float C1 = 0.063758817f;     // (1/sqrt(512)) * log2(e)

    __shared__ __align__(16) short Ksh[2][64 * ATP], Ksl[2][64 * ATP];
    __shared__ __align__(16) short Vth[2][64 * ATP], Vtl[2][64 * ATP];
    __shared__ unsigned Msk[2][2];

    const int t = threadIdx.x;
    const int w = t >> 6;
    const int lane = t & 63;
    const int lo5 = lane & 31;
    const int hi1 = lane >> 5;
    const int bh = blockIdx.x;          // XCD = (flat id)%8 = bh%8
    const int qt = blockIdx.y;
    const int qb0 = qt * 128;
    const int b = bh >> 3, h = bh & 7;

    // ---- Q fragments, in registers for the whole kernel
    short8 qf[4][2];
    const size_t qrow = ((size_t)(b * S + qb0 + w * 32 + lo5)) * 512 + h * 64;
#pragma unroll
    for (int ks = 0; ks < 4; ++ks) {
        qf[ks][0] = *(const short8*)(Qh + qrow + 8 * hi1 + 16 * ks);
        qf[ks][1] = *(const short8*)(Ql + qrow + 8 * hi1 + 16 * ks);
    }

    float m2 = -3.0e38f, l_ = 0.f;
    f32x16 acc[2];
    acc[0] = (f32x16)(0.f); acc[1] = (f32x16)(0.f);

    // ---- tile prefetch registers
    const int krow = t >> 2, ksq = t & 3;
    const int vk0 = (t & 31) * 2, vdb = (t >> 5) * 8;
    short8 pk[2][2], pv[2][2];
    int pm = 1;

    auto loadTile = [&](int kt) {
        const size_t kro = ((size_t)(b * S + kt * 64 + krow)) * 512 + h * 64;
        pk[0][0] = *(const short8*)(Kh + kro + ksq * 8);
        pk[0][1] = *(const short8*)(Kh + kro + ksq * 8 + 32);
        pk[1][0] = *(const short8*)(Kl + kro + ksq * 8);
        pk[1][1] = *(const short8*)(Kl + kro + ksq * 8 + 32);
        const size_t vro = ((size_t)(b * S + kt * 64 + vk0)) * 512 + h * 64 + vdb;
        pv[0][0] = *(const short8*)(Vh + vro);
        pv[0][1] = *(const short8*)(Vh + vro + 512);
        pv[1][0] = *(const short8*)(Vl + vro);
        pv[1][1] = *(const short8*)(Vl + vro + 512);
        if (t < 64) pm = mask[b * S + kt * 64 + t];
    };

    auto stage = [&](int buf) {
        *(short8*)&Ksh[buf][krow * ATP + ksq * 8]      = pk[0][0];
        *(short8*)&Ksh[buf][krow * ATP + ksq * 8 + 32] = pk[0][1];
        *(short8*)&Ksl[buf][krow * ATP + ksq * 8]      = pk[1][0];
        *(short8*)&Ksl[buf][krow * ATP + ksq * 8 + 32] = pk[1][1];
#pragma unroll
        for (int dd = 0; dd < 8; ++dd) {
            *(int*)&Vth[buf][(vdb + dd) * ATP + vk0] =
                (unsigned)(unsigned short)pv[0][0][dd] |
                ((unsigned)(unsigned short)pv[0][1][dd] << 16);
            *(int*)&Vtl[buf][(vdb + dd) * ATP + vk0] =
                (unsigned)(unsigned short)pv[1][0][dd] |
                ((unsigned)(unsigned short)pv[1][1][dd] << 16);
        }
        if (t < 64) {
            unsigned long long bm = __ballot(pm != 0);
            if (t == 0) { Msk[buf][0] = (unsigned)bm; Msk[buf][1] = (unsigned)(bm >> 32); }
        }
    };

    // prologue: tile 0 staged, tile 1 in regs
    loadTile(0);
    stage(0);
    loadTile(1);
    __syncthreads();

    for (int kt = 0; kt < 32; ++kt) {
        const int cur = kt & 1;

        // ---- S^T = K * Q^T
        f32x16 sacc[2];
        sacc[0] = (f32x16)(0.f); sacc[1] = (f32x16)(0.f);
        __builtin_amdgcn_s_setprio(1);
#pragma unroll
        for (int ks = 0; ks < 4; ++ks) {
            const int co = 8 * hi1 + 16 * ks;
#pragma unroll
            for (int fr = 0; fr < 2; ++fr) {
                short8 ah = *(const short8*)&Ksh[cur][(lo5 + 32 * fr) * ATP + co];
                short8 al = *(const short8*)&Ksl[cur][(lo5 + 32 * fr) * ATP + co];
                sacc[fr] = MFMA32(ah, qf[ks][0], sacc[fr]);
                sacc[fr] = MFMA32(ah, qf[ks][1], sacc[fr]);
                sacc[fr] = MFMA32(al, qf[ks][0], sacc[fr]);
            }
        }
        __builtin_amdgcn_s_setprio(0);

        // ---- mask + scale (log2 domain) + online softmax
        float tv[2][16];
        float mt = -3.0e38f;
#pragma unroll
        for (int fr = 0; fr < 2; ++fr) {
            const unsigned mws = Msk[cur][fr] >> (hi1 * 4);
#pragma unroll
            for (int reg = 0; reg < 16; ++reg) {
                const int bp = (reg & 3) + 8 * (reg >> 2);
                const float s = sacc[fr][reg];
                const float tt = ((mws >> bp) & 1u) ? s * C1 : -1.0e20f;
                tv[fr][reg] = tt;
                mt = fmaxf(mt, tt);
            }
        }
        mt = fmaxf(mt, __shfl_xor(mt, 32));
        const float mn = fmaxf(m2, mt);
        const float alpha = exp2f(m2 - mn);
        m2 = mn;
        float ps = 0.f;
#pragma unroll
        for (int fr = 0; fr < 2; ++fr)
#pragma unroll
            for (int reg = 0; reg < 16; ++reg) {
                const float p = exp2f(tv[fr][reg] - mn);
                tv[fr][reg] = p;
                ps += p;
            }
        ps += __shfl_xor(ps, 32);
        l_ = l_ * alpha + ps;
        acc[0] *= alpha;
        acc[1] *= alpha;

        // ---- pack P to bf16 hi/lo words (word 2bb+p2 = keys 8bb+4hi1+2p2,+1)
        unsigned pwh[16], pwl[16];
#pragma unroll
        for (int g8 = 0; g8 < 8; ++g8) {
            const int f = g8 >> 2, u4 = (g8 & 3) * 4;
#pragma unroll
            for (int p2 = 0; p2 < 2; ++p2) {
                const float v0 = tv[f][u4 + 2 * p2];
                const float v1 = tv[f][u4 + 2 * p2 + 1];
                const unsigned hw = cvt_pk_bf16(v0, v1);
                const float h0 = __uint_as_float(hw << 16);
                const float h1 = __uint_as_float(hw & 0xFFFF0000u);
                const unsigned lw = cvt_pk_bf16(v0 - h0, v1 - h1);
                pwh[g8 * 2 + p2] = hw;
                pwl[g8 * 2 + p2] = lw;
            }
        }

        // ---- out^T += V^T * P^T; B-frag built in-register via lane^32 swap
#pragma unroll
        for (int ks = 0; ks < 4; ++ks) {
            const int co = 8 * hi1 + 16 * ks;
            // hi plane
            const unsigned vA0h = pwh[4 * ks], vA1h = pwh[4 * ks + 1];
            const unsigned vB0h = pwh[4 * ks + 2], vB1h = pwh[4 * ks + 3];
            const unsigned r0h = (unsigned)__shfl_xor((int)(hi1 ? vA0h : vB0h), 32);
            const unsigned r1h = (unsigned)__shfl_xor((int)(hi1 ? vA1h : vB1h), 32);
            const short8 pbh = mk8(hi1 ? r0h : vA0h, hi1 ? r1h : vA1h,
                                   hi1 ? vB0h : r0h, hi1 ? vB1h : r1h);
            // lo plane
            const unsigned vA0l = pwl[4 * ks], vA1l = pwl[4 * ks + 1];
            const unsigned vB0l = pwl[4 * ks + 2], vB1l = pwl[4 * ks + 3];
            const unsigned r0l = (unsigned)__shfl_xor((int)(hi1 ? vA0l : vB0l), 32);
            const unsigned r1l = (unsigned)__shfl_xor((int)(hi1 ? vA1l : vB1l), 32);
            const short8 pbl = mk8(hi1 ? r0l : vA0l, hi1 ? r1l : vA1l,
                                   hi1 ? vB0l : r0l, hi1 ? vB1l : r1l);
            __builtin_amdgcn_s_setprio(1);
#pragma unroll
            for (int fr = 0; fr < 2; ++fr) {
                short8 vah = *(const short8*)&Vth[cur][(lo5 + 32 * fr) * ATP + co];
                short8 val = *(const short8*)&Vtl[cur][(lo5 + 32 * fr) * ATP + co];
                acc[fr] = MFMA32(vah, pbh, acc[fr]);
                acc[fr] = MFMA32(vah, pbl, acc[fr]);
                acc[fr] = MFMA32(val, pbh, acc[fr]);
            }
            __builtin_amdgcn_s_setprio(0);
        }

        // ---- stage next tile into the other buffer, prefetch tile kt+2
        if (kt < 31) {
            stage(cur ^ 1);
            if (kt < 30) loadTile(kt + 2);
            __syncthreads();
        }
    }

    // ---- epilogue: normalize, trunc-split, store planes
    const float inv = 1.0f / l_;
    const size_t orow = qrow;
#pragma unroll
    for (int fr = 0; fr < 2; ++fr)
#pragma unroll
        for (int rq = 0; rq < 4; ++rq) {
            float v[4];
            unsigned uh[4], ulo[4];
#pragma unroll
            for (int i = 0; i < 4; ++i) {
                v[i] = acc[fr][rq * 4 + i] * inv;
                unsigned u = __float_as_uint(v[i]);
                uh[i] = u & 0xFFFF0000u;
                ulo[i] = __float_as_uint(v[i] - __uint_as_float(uh[i]));
            }
            int2 hw, lw;
            hw.x = (int)((uh[1]) | (uh[0] >> 16));
            hw.y = (int)((uh[3]) | (uh[2] >> 16));
            lw.x = (int)((ulo[1] & 0xFFFF0000u) | (ulo[0] >> 16));
            lw.y = (int)((ulo[3] & 0xFFFF0000u) | (ulo[2] >> 16));
            const size_t off = orow + 8 * rq + 4 * hi1 + 32 * fr;
            *(int2*)&Oh[off] = hw;
            *(int2*)&Ol[off] = lw;
        }
}

// ---------------------------------------------------------------------------
extern "C" void kernel_launch(void* const* d_in, const int* in_sizes, int n_in,
                              void* d_out, int out_size, void* d_ws, size_t ws_size,
                              hipStream_t stream) {
    const float* values = (const float*)d_in[0];
    const float* keys   = (const float*)d_in[1];
    const float* query  = (const float*)d_in[2];
    const int*   mask   = (const int*)d_in[3];
    const float* Wv     = (const float*)d_in[4];
    const float* Wk     = (const float*)d_in[5];
    const float* Wq     = (const float*)d_in[6];
    const float* Wo     = (const float*)d_in[7];
    const float* bo     = (const float*)d_in[8];
    float* out = (float*)d_out;

    const size_t MB = 1024 * 1024;
    char* wsb = (char*)d_ws;
    short* Qhp = (short*)(wsb);
    short* Qlp = (short*)(wsb + 8 * MB);
    short* Khp = (short*)(wsb + 16 * MB);
    short* Klp = (short*)(wsb + 24 * MB);
    short* Vhp = (short*)(wsb + 32 * MB);
    short* Vlp = (short*)(wsb + 40 * MB);
    short* Ohp = (short*)(wsb + 48 * MB);
    short* Olp = (short*)(wsb + 56 * MB);
    short* Wqh = (short*)(wsb + 64 * MB);   short* Wql = Wqh + 262144;
    short* Wkh = Wql + 262144;              short* Wkl = Wkh + 262144;
    short* Wvh = Wkl + 262144;              short* Wvl = Wvh + 262144;
    short* Woh = Wvl + 262144;              short* Wol = Woh + 262144;
    (void)ws_size; (void)in_sizes; (void)n_in; (void)out_size;

    const int nW = 512 * 512 / 8;
    ConvArgs ca;
    ca.j[0] = {Wq, Wqh, Wql, nW};
    ca.j[1] = {Wk, Wkh, Wkl, nW};
    ca.j[2] = {Wv, Wvh, Wvl, nW};
    ca.j[3] = {Wo, Woh, Wol, nW};
    conv_split<<<dim3(128, 1, 4), 256, 0, stream>>>(ca);

    // q/k/v projections: fp32 X in, bf16 hi/lo planes out
    mfma_gemm<false, true><<<dim3(64, 4, 3), 256, 0, stream>>>(
        query,  nullptr, Wqh, Wql, Qhp, Qlp,
        keys,   nullptr, Wkh, Wkl, Khp, Klp,
        values, nullptr, Wvh, Wvl, Vhp, Vlp, nullptr);

    // fused attention on bf16 planes (grid: x=bh for XCD locality, y=qtile)
    attn_mfma<<<dim3(32, 16), 256, 0, stream>>>(
        Qhp, Qlp, Khp, Klp, Vhp, Vlp, mask, Ohp, Olp);

    // output projection: plane input, fp32 out + bias
    mfma_gemm<true, false><<<dim3(64, 4, 1), 256, 0, stream>>>(
        Ohp, Olp, Woh, Wol, out, nullptr,
        Ohp, Olp, Woh, Wol, out, nullptr,
        Ohp, Olp, Woh, Wol, out, nullptr, bo);
}